// Round 8
// baseline (175.742 us; speedup 1.0000x reference)
//
#include <hip/hip_runtime.h>
#include <hip/hip_bf16.h>
#include <math.h>

#define CIN 256
#define COUT 512

typedef __attribute__((ext_vector_type(8))) short bf16x8;
typedef __attribute__((ext_vector_type(4))) float f32x4;

__device__ __forceinline__ ushort f2bf(float f) {
    union { float f; unsigned u; } x; x.f = f;
    unsigned r = x.u + 0x7FFFu + ((x.u >> 16) & 1u);   // RNE
    return (ushort)(r >> 16);
}
__device__ __forceinline__ float bf2f(ushort u) {
    union { unsigned u; float f; } x; x.u = (unsigned)u << 16; return x.f;
}

__device__ __forceinline__ int lbound(const int* __restrict__ a, int n, int key) {
    int lo = 0, hi = n;
    while (lo < hi) {
        int m = (lo + hi) >> 1;
        if (a[m] < key) lo = m + 1; else hi = m;
    }
    return lo;
}

// ---------------------------------------------------------------------------
// Kernel A: three block-regions.
//   [0, nPool):           fused double max-pool. KEY: idx5 sorted => occupied
//                         slots of group g are consecutive idx5 positions
//                         [lb(8g), lb(8g+8)) => source data rows CONTIGUOUS.
//                         Branchless streaming max, clamp 0 iff cnt<8.
//   [nPool, nPool+32):    W (512x256 fp32) -> bf16 Wb.
//   [nPool+32, +64 more): inv4 scatter + gap-fill (R3-proven logic).
// ---------------------------------------------------------------------------
__global__ __launch_bounds__(256) void pool_prep_kernel(const float* __restrict__ data,
                                                        const int* __restrict__ idx5, int n_i5,
                                                        const int* __restrict__ idx4, int n_i4,
                                                        const float* __restrict__ W,
                                                        ushort* __restrict__ Wb,
                                                        ushort* __restrict__ P, int G2,
                                                        int* __restrict__ inv4, int n4) {
    const int b = blockIdx.x;
    const int nPool = G2 >> 2;
    const int t = threadIdx.x;

    if (b >= nPool) {
        int rb = b - nPool;
        if (rb < 32) {                       // W conversion: 32 blocks
            int q0 = rb * 1024 + t;
            #pragma unroll
            for (int j = 0; j < 4; ++j) {
                int i = (q0 + j * 256) * 4;
                float4 v = *reinterpret_cast<const float4*>(W + i);
                ushort4 o;
                o.x = f2bf(v.x); o.y = f2bf(v.y); o.z = f2bf(v.z); o.w = f2bf(v.w);
                *reinterpret_cast<ushort4*>(&Wb[i]) = o;
            }
        } else {                             // inv4 build: 64 blocks
            int i = (rb - 32) * 256 + t;
            if (i < n_i4) {
                int s = idx4[i];
                inv4[s] = i;
                int e = (i + 1 < n_i4) ? idx4[i + 1] : n4;
                for (int k = s + 1; k < e; ++k) inv4[k] = -1;
                if (i == 0) for (int k = 0; k < s; ++k) inv4[k] = -1;
            }
        }
        return;
    }

    // pooled rows g = b*4 + w, w=0..3; slot range of g: [8g, 8g+8) = [32b+8w, +8)
    __shared__ int lb[5];
    if (t < 5) lb[t] = lbound(idx5, n_i5, b * 32 + t * 8);
    __syncthreads();

    const int w = t >> 6, lane = t & 63;
    int lo  = __builtin_amdgcn_readfirstlane(lb[w]);
    int cnt = __builtin_amdgcn_readfirstlane(lb[w + 1]) - lo;   // occupied slots (0..8)

    float4 acc = make_float4(-INFINITY, -INFINITY, -INFINITY, -INFINITY);
    const float* base = data + (size_t)lo * (8 * CIN) + lane * 4;
    for (int j = 0; j < cnt; ++j) {          // contiguous: rows [8*lo, 8*(lo+cnt))
        #pragma unroll
        for (int r = 0; r < 8; ++r) {
            float4 v = *reinterpret_cast<const float4*>(base + ((size_t)j * 8 + r) * CIN);
            acc.x = fmaxf(acc.x, v.x);
            acc.y = fmaxf(acc.y, v.y);
            acc.z = fmaxf(acc.z, v.z);
            acc.w = fmaxf(acc.w, v.w);
        }
    }
    if (cnt < 8) {                           // empty slots contribute 0 (also cnt==0)
        acc.x = fmaxf(acc.x, 0.f);
        acc.y = fmaxf(acc.y, 0.f);
        acc.z = fmaxf(acc.z, 0.f);
        acc.w = fmaxf(acc.w, 0.f);
    }
    ushort4 o;
    o.x = f2bf(acc.x); o.y = f2bf(acc.y); o.z = f2bf(acc.z); o.w = f2bf(acc.w);
    *reinterpret_cast<ushort4*>(&P[(size_t)(b * 4 + w) * CIN + lane * 4]) = o;
}

// ---------------------------------------------------------------------------
// Kernel B: bf16 MFMA GEMM + fused column stats (R3/R7-proven, unchanged).
// ---------------------------------------------------------------------------
__global__ __launch_bounds__(256) void mfma_gemm_kernel(const ushort* __restrict__ A,
                                                        const ushort* __restrict__ B,
                                                        ushort* __restrict__ H,
                                                        float* __restrict__ partial) {
    __shared__ __align__(16) ushort Asm[128 * 64];
    __shared__ __align__(16) ushort Bsm[128 * 64];

    int t = threadIdx.x;
    int lane = t & 63;
    int wid = t >> 6;
    int wm = wid >> 1, wn = wid & 1;
    int m0 = blockIdx.x * 128, n0 = blockIdx.y * 128;

    f32x4 acc[4][4] = {};

    for (int k0 = 0; k0 < CIN; k0 += 64) {
        #pragma unroll
        for (int i = 0; i < 4; ++i) {
            int idx = i * 256 + t;          // 0..1023
            int row = idx >> 3;
            int sl  = idx & 7;
            bf16x8 av = *reinterpret_cast<const bf16x8*>(A + (size_t)(m0 + row) * CIN + k0 + sl * 8);
            bf16x8 bv = *reinterpret_cast<const bf16x8*>(B + (size_t)(n0 + row) * CIN + k0 + sl * 8);
            int ws = (sl ^ (row & 7)) * 8;
            *reinterpret_cast<bf16x8*>(&Asm[row * 64 + ws]) = av;
            *reinterpret_cast<bf16x8*>(&Bsm[row * 64 + ws]) = bv;
        }
        __syncthreads();

        #pragma unroll
        for (int ks = 0; ks < 2; ++ks) {
            bf16x8 af[4], bfr[4];
            int slog = ks * 4 + (lane >> 4);
            #pragma unroll
            for (int mi = 0; mi < 4; ++mi) {
                int row = wm * 64 + mi * 16 + (lane & 15);
                af[mi] = *reinterpret_cast<const bf16x8*>(&Asm[row * 64 + (slog ^ (row & 7)) * 8]);
            }
            #pragma unroll
            for (int ni = 0; ni < 4; ++ni) {
                int col = wn * 64 + ni * 16 + (lane & 15);
                bfr[ni] = *reinterpret_cast<const bf16x8*>(&Bsm[col * 64 + (slog ^ (col & 7)) * 8]);
            }
            #pragma unroll
            for (int mi = 0; mi < 4; ++mi)
                #pragma unroll
                for (int ni = 0; ni < 4; ++ni)
                    acc[mi][ni] = __builtin_amdgcn_mfma_f32_16x16x32_bf16(af[mi], bfr[ni], acc[mi][ni], 0, 0, 0);
        }
        __syncthreads();
    }

    // fused column stats
    float s[4], q[4];
    #pragma unroll
    for (int ni = 0; ni < 4; ++ni) {
        s[ni] = 0.f; q[ni] = 0.f;
        #pragma unroll
        for (int mi = 0; mi < 4; ++mi)
            #pragma unroll
            for (int r = 0; r < 4; ++r) {
                float v = acc[mi][ni][r];
                s[ni] += v;
                q[ni] = fmaf(v, v, q[ni]);
            }
        s[ni] += __shfl_xor(s[ni], 16); s[ni] += __shfl_xor(s[ni], 32);
        q[ni] += __shfl_xor(q[ni], 16); q[ni] += __shfl_xor(q[ni], 32);
    }
    float* redS = (float*)Asm;
    float* redQ = redS + 256;
    if (lane < 16) {
        #pragma unroll
        for (int ni = 0; ni < 4; ++ni) {
            int c = wn * 64 + ni * 16 + lane;
            redS[wm * 128 + c] = s[ni];
            redQ[wm * 128 + c] = q[ni];
        }
    }
    __syncthreads();
    if (t < 128) {
        float S = redS[t] + redS[128 + t];
        float Q = redQ[t] + redQ[128 + t];
        partial[(size_t)blockIdx.x * 1024 + blockIdx.y * 128 + t]       = S;
        partial[(size_t)blockIdx.x * 1024 + 512 + blockIdx.y * 128 + t] = Q;
    }

    // H write (bf16)
    #pragma unroll
    for (int mi = 0; mi < 4; ++mi) {
        #pragma unroll
        for (int ni = 0; ni < 4; ++ni) {
            int col   = n0 + wn * 64 + ni * 16 + (lane & 15);
            int rbase = m0 + wm * 64 + mi * 16 + (lane >> 4) * 4;
            #pragma unroll
            for (int r = 0; r < 4; ++r)
                H[(size_t)(rbase + r) * COUT + col] = f2bf(acc[mi][ni][r]);
        }
    }
}

// ---------------------------------------------------------------------------
// Kernel C: finalize BN scale/shift (proven)
// ---------------------------------------------------------------------------
__global__ __launch_bounds__(256) void bn_finalize_kernel(const float* __restrict__ partial, int nparts,
                                                          const float* __restrict__ gamma,
                                                          const float* __restrict__ beta,
                                                          float* __restrict__ scale,
                                                          float* __restrict__ shift,
                                                          float invN) {
    int c = blockIdx.x * blockDim.x + threadIdx.x;
    if (c >= COUT) return;
    float s = 0.f, q = 0.f;
    for (int p = 0; p < nparts; ++p) {
        s += partial[(size_t)p * 1024 + c];
        q += partial[(size_t)p * 1024 + 512 + c];
    }
    float mean = s * invN;
    float var  = fmaf(q, invN, -mean * mean);
    float inv  = rsqrtf(var + 1e-5f);
    float sc   = gamma[c] * inv;
    scale[c] = sc;
    shift[c] = fmaf(-mean, sc, beta[c]);
}

// ---------------------------------------------------------------------------
// Kernel D: normalize + relu + scatter (proven; H is bf16)
// ---------------------------------------------------------------------------
__global__ __launch_bounds__(256) void out_kernel(const ushort* __restrict__ H,
                                                  const int* __restrict__ inv4,
                                                  const float* __restrict__ scale,
                                                  const float* __restrict__ shift,
                                                  float* __restrict__ out, int rows) {
    int t = blockIdx.x * blockDim.x + threadIdx.x;
    int m = t >> 7;
    int qd = t & 127;
    if (m >= rows) return;
    int c = qd * 4;
    int j = inv4[m];
    float4 sc = *reinterpret_cast<const float4*>(&scale[c]);
    float4 sh = *reinterpret_cast<const float4*>(&shift[c]);
    float4 r;
    if (j >= 0) {
        ushort4 h = *reinterpret_cast<const ushort4*>(&H[(size_t)j * COUT + c]);
        r.x = fmaxf(fmaf(bf2f(h.x), sc.x, sh.x), 0.f);
        r.y = fmaxf(fmaf(bf2f(h.y), sc.y, sh.y), 0.f);
        r.z = fmaxf(fmaf(bf2f(h.z), sc.z, sh.z), 0.f);
        r.w = fmaxf(fmaf(bf2f(h.w), sc.w, sh.w), 0.f);
    } else {
        r.x = fmaxf(sh.x, 0.f);
        r.y = fmaxf(sh.y, 0.f);
        r.z = fmaxf(sh.z, 0.f);
        r.w = fmaxf(sh.w, 0.f);
    }
    *reinterpret_cast<float4*>(&out[(size_t)m * COUT + c]) = r;
}

// ---------------------------------------------------------------------------
extern "C" void kernel_launch(void* const* d_in, const int* in_sizes, int n_in,
                              void* d_out, int out_size, void* d_ws, size_t ws_size,
                              hipStream_t stream) {
    const float* data   = (const float*)d_in[0];
    const float* weight = (const float*)d_in[1];
    const float* gamma  = (const float*)d_in[2];
    const float* beta   = (const float*)d_in[3];
    const int*   idx5   = (const int*)d_in[4];
    const int*   idx4   = (const int*)d_in[5];

    const int n_i5 = in_sizes[4];        // 65536
    const int n_i4 = in_sizes[5];        // 16384
    const int G2   = n_i4;
    const int rows = out_size / COUT;    // 32768
    const int M    = G2;                 // 16384
    const int MB   = M / 128;            // 128 m-tiles

    // workspace layout
    char* w = (char*)d_ws;
    ushort* P      = (ushort*)w;                        w += (size_t)G2 * CIN * sizeof(ushort);    // 8 MiB
    ushort* H      = (ushort*)w;                        w += (size_t)G2 * COUT * sizeof(ushort);   // 16 MiB
    ushort* Wb     = (ushort*)w;                        w += (size_t)COUT * CIN * sizeof(ushort);  // 0.25 MiB
    float* partial = (float*)w;                         w += (size_t)MB * 1024 * sizeof(float);    // 512 KiB
    float* scale   = (float*)w;                         w += COUT * sizeof(float);
    float* shift   = (float*)w;                         w += COUT * sizeof(float);
    int*   inv4    = (int*)w;                           w += (size_t)rows * sizeof(int);           // 128 KiB

    // A: pool (G2/4 blocks) + W->bf16 (32 blocks) + inv4 build (64 blocks)
    pool_prep_kernel<<<G2 / 4 + 32 + (n_i4 + 255) / 256, 256, 0, stream>>>(
        data, idx5, n_i5, idx4, n_i4, weight, Wb, P, G2, inv4, rows);

    // B: MFMA GEMM + fused stats
    {
        dim3 grid(MB, COUT / 128);
        mfma_gemm_kernel<<<grid, 256, 0, stream>>>(P, Wb, H, partial);
    }
    // C: finalize BN scale/shift
    bn_finalize_kernel<<<2, 256, 0, stream>>>(partial, MB, gamma, beta, scale, shift,
                                              1.0f / (float)rows);
    // D: normalize + relu + scatter
    out_kernel<<<((size_t)rows * 128 + 255) / 256, 256, 0, stream>>>(H, inv4, scale, shift,
                                                                     (float*)d_out, rows);
}

// Round 9
// 155.569 us; speedup vs baseline: 1.1297x; 1.1297x over previous
//
#include <hip/hip_runtime.h>
#include <hip/hip_bf16.h>
#include <math.h>

#define CIN 256
#define COUT 512

typedef __attribute__((ext_vector_type(8))) short bf16x8;
typedef __attribute__((ext_vector_type(4))) float f32x4;
typedef __attribute__((ext_vector_type(4))) float f32x4v;

__device__ __forceinline__ ushort f2bf(float f) {
    union { float f; unsigned u; } x; x.f = f;
    unsigned r = x.u + 0x7FFFu + ((x.u >> 16) & 1u);   // RNE
    return (ushort)(r >> 16);
}
__device__ __forceinline__ float bf2f(ushort u) {
    union { unsigned u; float f; } x; x.u = (unsigned)u << 16; return x.f;
}

__device__ __forceinline__ int lbound(const int* __restrict__ a, int n, int key) {
    int lo = 0, hi = n;
    while (lo < hi) {
        int m = (lo + hi) >> 1;
        if (a[m] < key) lo = m + 1; else hi = m;
    }
    return lo;
}

// ---------------------------------------------------------------------------
// Kernel A: three block-regions.
//   [0, nPool):  fused double max-pool. idx5 sorted => occupied slots of group
//     g are consecutive idx5 positions [lb(8g), lb(8g+8)) => source rows
//     CONTIGUOUS [8*lo, 8*(lo+cnt)). PREDICATED FULL UNROLL (j<8, if j<cnt):
//     keeps ~64 loads in flight (R8's dynamic loop serialized at 8 -> +20us).
//   [nPool, nPool+32):    W (512x256 fp32) -> bf16 Wb.
//   [nPool+32, +64 more): inv4 scatter + gap-fill (proven).
// ---------------------------------------------------------------------------
__global__ __launch_bounds__(256) void pool_prep_kernel(const float* __restrict__ data,
                                                        const int* __restrict__ idx5, int n_i5,
                                                        const int* __restrict__ idx4, int n_i4,
                                                        const float* __restrict__ W,
                                                        ushort* __restrict__ Wb,
                                                        ushort* __restrict__ P, int G2,
                                                        int* __restrict__ inv4, int n4) {
    const int b = blockIdx.x;
    const int nPool = G2 >> 2;
    const int t = threadIdx.x;

    if (b >= nPool) {
        int rb = b - nPool;
        if (rb < 32) {                       // W conversion: 32 blocks
            int q0 = rb * 1024 + t;
            #pragma unroll
            for (int j = 0; j < 4; ++j) {
                int i = (q0 + j * 256) * 4;
                float4 v = *reinterpret_cast<const float4*>(W + i);
                ushort4 o;
                o.x = f2bf(v.x); o.y = f2bf(v.y); o.z = f2bf(v.z); o.w = f2bf(v.w);
                *reinterpret_cast<ushort4*>(&Wb[i]) = o;
            }
        } else {                             // inv4 build: 64 blocks
            int i = (rb - 32) * 256 + t;
            if (i < n_i4) {
                int s = idx4[i];
                inv4[s] = i;
                int e = (i + 1 < n_i4) ? idx4[i + 1] : n4;
                for (int k = s + 1; k < e; ++k) inv4[k] = -1;
                if (i == 0) for (int k = 0; k < s; ++k) inv4[k] = -1;
            }
        }
        return;
    }

    // pooled rows g = b*4 + w; slot range of g: [32b+8w, +8)
    __shared__ int lb[5];
    if (t < 5) lb[t] = lbound(idx5, n_i5, b * 32 + t * 8);
    __syncthreads();

    const int w = t >> 6, lane = t & 63;
    int lo  = __builtin_amdgcn_readfirstlane(lb[w]);
    int cnt = __builtin_amdgcn_readfirstlane(lb[w + 1]) - lo;   // 0..8 occupied

    float4 acc = make_float4(-INFINITY, -INFINITY, -INFINITY, -INFINITY);
    const float* base = data + (size_t)lo * (8 * CIN) + lane * 4;
    #pragma unroll
    for (int j = 0; j < 8; ++j) {
        if (j < cnt) {                       // wave-uniform predicate, unrolled
            #pragma unroll
            for (int r = 0; r < 8; ++r) {
                f32x4v v = __builtin_nontemporal_load(
                    reinterpret_cast<const f32x4v*>(base + ((size_t)j * 8 + r) * CIN));
                acc.x = fmaxf(acc.x, v.x);
                acc.y = fmaxf(acc.y, v.y);
                acc.z = fmaxf(acc.z, v.z);
                acc.w = fmaxf(acc.w, v.w);
            }
        }
    }
    if (cnt < 8) {                           // empty slots contribute 0 (also cnt==0)
        acc.x = fmaxf(acc.x, 0.f);
        acc.y = fmaxf(acc.y, 0.f);
        acc.z = fmaxf(acc.z, 0.f);
        acc.w = fmaxf(acc.w, 0.f);
    }
    ushort4 o;
    o.x = f2bf(acc.x); o.y = f2bf(acc.y); o.z = f2bf(acc.z); o.w = f2bf(acc.w);
    *reinterpret_cast<ushort4*>(&P[(size_t)(b * 4 + w) * CIN + lane * 4]) = o;
}

// ---------------------------------------------------------------------------
// Kernel B: bf16 MFMA GEMM + fused column stats (proven, unchanged).
// ---------------------------------------------------------------------------
__global__ __launch_bounds__(256) void mfma_gemm_kernel(const ushort* __restrict__ A,
                                                        const ushort* __restrict__ B,
                                                        ushort* __restrict__ H,
                                                        float* __restrict__ partial) {
    __shared__ __align__(16) ushort Asm[128 * 64];
    __shared__ __align__(16) ushort Bsm[128 * 64];

    int t = threadIdx.x;
    int lane = t & 63;
    int wid = t >> 6;
    int wm = wid >> 1, wn = wid & 1;
    int m0 = blockIdx.x * 128, n0 = blockIdx.y * 128;

    f32x4 acc[4][4] = {};

    for (int k0 = 0; k0 < CIN; k0 += 64) {
        #pragma unroll
        for (int i = 0; i < 4; ++i) {
            int idx = i * 256 + t;          // 0..1023
            int row = idx >> 3;
            int sl  = idx & 7;
            bf16x8 av = *reinterpret_cast<const bf16x8*>(A + (size_t)(m0 + row) * CIN + k0 + sl * 8);
            bf16x8 bv = *reinterpret_cast<const bf16x8*>(B + (size_t)(n0 + row) * CIN + k0 + sl * 8);
            int ws = (sl ^ (row & 7)) * 8;
            *reinterpret_cast<bf16x8*>(&Asm[row * 64 + ws]) = av;
            *reinterpret_cast<bf16x8*>(&Bsm[row * 64 + ws]) = bv;
        }
        __syncthreads();

        #pragma unroll
        for (int ks = 0; ks < 2; ++ks) {
            bf16x8 af[4], bfr[4];
            int slog = ks * 4 + (lane >> 4);
            #pragma unroll
            for (int mi = 0; mi < 4; ++mi) {
                int row = wm * 64 + mi * 16 + (lane & 15);
                af[mi] = *reinterpret_cast<const bf16x8*>(&Asm[row * 64 + (slog ^ (row & 7)) * 8]);
            }
            #pragma unroll
            for (int ni = 0; ni < 4; ++ni) {
                int col = wn * 64 + ni * 16 + (lane & 15);
                bfr[ni] = *reinterpret_cast<const bf16x8*>(&Bsm[col * 64 + (slog ^ (col & 7)) * 8]);
            }
            #pragma unroll
            for (int mi = 0; mi < 4; ++mi)
                #pragma unroll
                for (int ni = 0; ni < 4; ++ni)
                    acc[mi][ni] = __builtin_amdgcn_mfma_f32_16x16x32_bf16(af[mi], bfr[ni], acc[mi][ni], 0, 0, 0);
        }
        __syncthreads();
    }

    // fused column stats
    float s[4], q[4];
    #pragma unroll
    for (int ni = 0; ni < 4; ++ni) {
        s[ni] = 0.f; q[ni] = 0.f;
        #pragma unroll
        for (int mi = 0; mi < 4; ++mi)
            #pragma unroll
            for (int r = 0; r < 4; ++r) {
                float v = acc[mi][ni][r];
                s[ni] += v;
                q[ni] = fmaf(v, v, q[ni]);
            }
        s[ni] += __shfl_xor(s[ni], 16); s[ni] += __shfl_xor(s[ni], 32);
        q[ni] += __shfl_xor(q[ni], 16); q[ni] += __shfl_xor(q[ni], 32);
    }
    float* redS = (float*)Asm;
    float* redQ = redS + 256;
    if (lane < 16) {
        #pragma unroll
        for (int ni = 0; ni < 4; ++ni) {
            int c = wn * 64 + ni * 16 + lane;
            redS[wm * 128 + c] = s[ni];
            redQ[wm * 128 + c] = q[ni];
        }
    }
    __syncthreads();
    if (t < 128) {
        float S = redS[t] + redS[128 + t];
        float Q = redQ[t] + redQ[128 + t];
        partial[(size_t)blockIdx.x * 1024 + blockIdx.y * 128 + t]       = S;
        partial[(size_t)blockIdx.x * 1024 + 512 + blockIdx.y * 128 + t] = Q;
    }

    // H write (bf16)
    #pragma unroll
    for (int mi = 0; mi < 4; ++mi) {
        #pragma unroll
        for (int ni = 0; ni < 4; ++ni) {
            int col   = n0 + wn * 64 + ni * 16 + (lane & 15);
            int rbase = m0 + wm * 64 + mi * 16 + (lane >> 4) * 4;
            #pragma unroll
            for (int r = 0; r < 4; ++r)
                H[(size_t)(rbase + r) * COUT + col] = f2bf(acc[mi][ni][r]);
        }
    }
}

// ---------------------------------------------------------------------------
// Kernel C: finalize BN scale/shift (proven)
// ---------------------------------------------------------------------------
__global__ __launch_bounds__(256) void bn_finalize_kernel(const float* __restrict__ partial, int nparts,
                                                          const float* __restrict__ gamma,
                                                          const float* __restrict__ beta,
                                                          float* __restrict__ scale,
                                                          float* __restrict__ shift,
                                                          float invN) {
    int c = blockIdx.x * blockDim.x + threadIdx.x;
    if (c >= COUT) return;
    float s = 0.f, q = 0.f;
    for (int p = 0; p < nparts; ++p) {
        s += partial[(size_t)p * 1024 + c];
        q += partial[(size_t)p * 1024 + 512 + c];
    }
    float mean = s * invN;
    float var  = fmaf(q, invN, -mean * mean);
    float inv  = rsqrtf(var + 1e-5f);
    float sc   = gamma[c] * inv;
    scale[c] = sc;
    shift[c] = fmaf(-mean, sc, beta[c]);
}

// ---------------------------------------------------------------------------
// Kernel D: normalize + relu + scatter (proven; H is bf16)
// ---------------------------------------------------------------------------
__global__ __launch_bounds__(256) void out_kernel(const ushort* __restrict__ H,
                                                  const int* __restrict__ inv4,
                                                  const float* __restrict__ scale,
                                                  const float* __restrict__ shift,
                                                  float* __restrict__ out, int rows) {
    int t = blockIdx.x * blockDim.x + threadIdx.x;
    int m = t >> 7;
    int qd = t & 127;
    if (m >= rows) return;
    int c = qd * 4;
    int j = inv4[m];
    float4 sc = *reinterpret_cast<const float4*>(&scale[c]);
    float4 sh = *reinterpret_cast<const float4*>(&shift[c]);
    float4 r;
    if (j >= 0) {
        ushort4 h = *reinterpret_cast<const ushort4*>(&H[(size_t)j * COUT + c]);
        r.x = fmaxf(fmaf(bf2f(h.x), sc.x, sh.x), 0.f);
        r.y = fmaxf(fmaf(bf2f(h.y), sc.y, sh.y), 0.f);
        r.z = fmaxf(fmaf(bf2f(h.z), sc.z, sh.z), 0.f);
        r.w = fmaxf(fmaf(bf2f(h.w), sc.w, sh.w), 0.f);
    } else {
        r.x = fmaxf(sh.x, 0.f);
        r.y = fmaxf(sh.y, 0.f);
        r.z = fmaxf(sh.z, 0.f);
        r.w = fmaxf(sh.w, 0.f);
    }
    *reinterpret_cast<float4*>(&out[(size_t)m * COUT + c]) = r;
}

// ---------------------------------------------------------------------------
extern "C" void kernel_launch(void* const* d_in, const int* in_sizes, int n_in,
                              void* d_out, int out_size, void* d_ws, size_t ws_size,
                              hipStream_t stream) {
    const float* data   = (const float*)d_in[0];
    const float* weight = (const float*)d_in[1];
    const float* gamma  = (const float*)d_in[2];
    const float* beta   = (const float*)d_in[3];
    const int*   idx5   = (const int*)d_in[4];
    const int*   idx4   = (const int*)d_in[5];

    const int n_i5 = in_sizes[4];        // 65536
    const int n_i4 = in_sizes[5];        // 16384
    const int G2   = n_i4;
    const int rows = out_size / COUT;    // 32768
    const int M    = G2;                 // 16384
    const int MB   = M / 128;            // 128 m-tiles

    // workspace layout
    char* w = (char*)d_ws;
    ushort* P      = (ushort*)w;                        w += (size_t)G2 * CIN * sizeof(ushort);    // 8 MiB
    ushort* H      = (ushort*)w;                        w += (size_t)G2 * COUT * sizeof(ushort);   // 16 MiB
    ushort* Wb     = (ushort*)w;                        w += (size_t)COUT * CIN * sizeof(ushort);  // 0.25 MiB
    float* partial = (float*)w;                         w += (size_t)MB * 1024 * sizeof(float);    // 512 KiB
    float* scale   = (float*)w;                         w += COUT * sizeof(float);
    float* shift   = (float*)w;                         w += COUT * sizeof(float);
    int*   inv4    = (int*)w;                           w += (size_t)rows * sizeof(int);           // 128 KiB

    // A: pool (G2/4 blocks) + W->bf16 (32 blocks) + inv4 build (64 blocks)
    pool_prep_kernel<<<G2 / 4 + 32 + (n_i4 + 255) / 256, 256, 0, stream>>>(
        data, idx5, n_i5, idx4, n_i4, weight, Wb, P, G2, inv4, rows);

    // B: MFMA GEMM + fused stats
    {
        dim3 grid(MB, COUT / 128);
        mfma_gemm_kernel<<<grid, 256, 0, stream>>>(P, Wb, H, partial);
    }
    // C: finalize BN scale/shift
    bn_finalize_kernel<<<2, 256, 0, stream>>>(partial, MB, gamma, beta, scale, shift,
                                              1.0f / (float)rows);
    // D: normalize + relu + scatter
    out_kernel<<<((size_t)rows * 128 + 255) / 256, 256, 0, stream>>>(H, inv4, scale, shift,
                                                                     (float*)d_out, rows);
}

// Round 10
// 129.592 us; speedup vs baseline: 1.3561x; 1.2005x over previous
//
#include <hip/hip_runtime.h>
#include <hip/hip_bf16.h>
#include <math.h>

#define CIN 256
#define COUT 512

typedef __attribute__((ext_vector_type(8))) short bf16x8;
typedef __attribute__((ext_vector_type(4))) float f32x4;
typedef __attribute__((ext_vector_type(4))) float f32x4v;

__device__ __forceinline__ ushort f2bf(float f) {
    union { float f; unsigned u; } x; x.f = f;
    unsigned r = x.u + 0x7FFFu + ((x.u >> 16) & 1u);   // RNE
    return (ushort)(r >> 16);
}
__device__ __forceinline__ float bf2f(ushort u) {
    union { unsigned u; float f; } x; x.u = (unsigned)u << 16; return x.f;
}

__device__ __forceinline__ int lbound(const int* __restrict__ a, int n, int key) {
    int lo = 0, hi = n;
    while (lo < hi) {
        int m = (lo + hi) >> 1;
        if (a[m] < key) lo = m + 1; else hi = m;
    }
    return lo;
}

// ---------------------------------------------------------------------------
// Kernel A: unchanged from R9 (155 us baseline component).
// ---------------------------------------------------------------------------
__global__ __launch_bounds__(256) void pool_prep_kernel(const float* __restrict__ data,
                                                        const int* __restrict__ idx5, int n_i5,
                                                        const int* __restrict__ idx4, int n_i4,
                                                        const float* __restrict__ W,
                                                        ushort* __restrict__ Wb,
                                                        ushort* __restrict__ P, int G2,
                                                        int* __restrict__ inv4, int n4) {
    const int b = blockIdx.x;
    const int nPool = G2 >> 2;
    const int t = threadIdx.x;

    if (b >= nPool) {
        int rb = b - nPool;
        if (rb < 32) {                       // W conversion: 32 blocks
            int q0 = rb * 1024 + t;
            #pragma unroll
            for (int j = 0; j < 4; ++j) {
                int i = (q0 + j * 256) * 4;
                float4 v = *reinterpret_cast<const float4*>(W + i);
                ushort4 o;
                o.x = f2bf(v.x); o.y = f2bf(v.y); o.z = f2bf(v.z); o.w = f2bf(v.w);
                *reinterpret_cast<ushort4*>(&Wb[i]) = o;
            }
        } else {                             // inv4 build: 64 blocks
            int i = (rb - 32) * 256 + t;
            if (i < n_i4) {
                int s = idx4[i];
                inv4[s] = i;
                int e = (i + 1 < n_i4) ? idx4[i + 1] : n4;
                for (int k = s + 1; k < e; ++k) inv4[k] = -1;
                if (i == 0) for (int k = 0; k < s; ++k) inv4[k] = -1;
            }
        }
        return;
    }

    __shared__ int lb[5];
    if (t < 5) lb[t] = lbound(idx5, n_i5, b * 32 + t * 8);
    __syncthreads();

    const int w = t >> 6, lane = t & 63;
    int lo  = __builtin_amdgcn_readfirstlane(lb[w]);
    int cnt = __builtin_amdgcn_readfirstlane(lb[w + 1]) - lo;   // 0..8 occupied

    float4 acc = make_float4(-INFINITY, -INFINITY, -INFINITY, -INFINITY);
    const float* base = data + (size_t)lo * (8 * CIN) + lane * 4;
    #pragma unroll
    for (int j = 0; j < 8; ++j) {
        if (j < cnt) {                       // wave-uniform predicate, unrolled
            #pragma unroll
            for (int r = 0; r < 8; ++r) {
                f32x4v v = __builtin_nontemporal_load(
                    reinterpret_cast<const f32x4v*>(base + ((size_t)j * 8 + r) * CIN));
                acc.x = fmaxf(acc.x, v.x);
                acc.y = fmaxf(acc.y, v.y);
                acc.z = fmaxf(acc.z, v.z);
                acc.w = fmaxf(acc.w, v.w);
            }
        }
    }
    if (cnt < 8) {
        acc.x = fmaxf(acc.x, 0.f);
        acc.y = fmaxf(acc.y, 0.f);
        acc.z = fmaxf(acc.z, 0.f);
        acc.w = fmaxf(acc.w, 0.f);
    }
    ushort4 o;
    o.x = f2bf(acc.x); o.y = f2bf(acc.y); o.z = f2bf(acc.z); o.w = f2bf(acc.w);
    *reinterpret_cast<ushort4*>(&P[(size_t)(b * 4 + w) * CIN + lane * 4]) = o;
}

// ---------------------------------------------------------------------------
// Kernel B: bf16 MFMA GEMM + fused column stats (proven, unchanged).
// ---------------------------------------------------------------------------
__global__ __launch_bounds__(256) void mfma_gemm_kernel(const ushort* __restrict__ A,
                                                        const ushort* __restrict__ B,
                                                        ushort* __restrict__ H,
                                                        float* __restrict__ partial) {
    __shared__ __align__(16) ushort Asm[128 * 64];
    __shared__ __align__(16) ushort Bsm[128 * 64];

    int t = threadIdx.x;
    int lane = t & 63;
    int wid = t >> 6;
    int wm = wid >> 1, wn = wid & 1;
    int m0 = blockIdx.x * 128, n0 = blockIdx.y * 128;

    f32x4 acc[4][4] = {};

    for (int k0 = 0; k0 < CIN; k0 += 64) {
        #pragma unroll
        for (int i = 0; i < 4; ++i) {
            int idx = i * 256 + t;          // 0..1023
            int row = idx >> 3;
            int sl  = idx & 7;
            bf16x8 av = *reinterpret_cast<const bf16x8*>(A + (size_t)(m0 + row) * CIN + k0 + sl * 8);
            bf16x8 bv = *reinterpret_cast<const bf16x8*>(B + (size_t)(n0 + row) * CIN + k0 + sl * 8);
            int ws = (sl ^ (row & 7)) * 8;
            *reinterpret_cast<bf16x8*>(&Asm[row * 64 + ws]) = av;
            *reinterpret_cast<bf16x8*>(&Bsm[row * 64 + ws]) = bv;
        }
        __syncthreads();

        #pragma unroll
        for (int ks = 0; ks < 2; ++ks) {
            bf16x8 af[4], bfr[4];
            int slog = ks * 4 + (lane >> 4);
            #pragma unroll
            for (int mi = 0; mi < 4; ++mi) {
                int row = wm * 64 + mi * 16 + (lane & 15);
                af[mi] = *reinterpret_cast<const bf16x8*>(&Asm[row * 64 + (slog ^ (row & 7)) * 8]);
            }
            #pragma unroll
            for (int ni = 0; ni < 4; ++ni) {
                int col = wn * 64 + ni * 16 + (lane & 15);
                bfr[ni] = *reinterpret_cast<const bf16x8*>(&Bsm[col * 64 + (slog ^ (col & 7)) * 8]);
            }
            #pragma unroll
            for (int mi = 0; mi < 4; ++mi)
                #pragma unroll
                for (int ni = 0; ni < 4; ++ni)
                    acc[mi][ni] = __builtin_amdgcn_mfma_f32_16x16x32_bf16(af[mi], bfr[ni], acc[mi][ni], 0, 0, 0);
        }
        __syncthreads();
    }

    // fused column stats
    float s[4], q[4];
    #pragma unroll
    for (int ni = 0; ni < 4; ++ni) {
        s[ni] = 0.f; q[ni] = 0.f;
        #pragma unroll
        for (int mi = 0; mi < 4; ++mi)
            #pragma unroll
            for (int r = 0; r < 4; ++r) {
                float v = acc[mi][ni][r];
                s[ni] += v;
                q[ni] = fmaf(v, v, q[ni]);
            }
        s[ni] += __shfl_xor(s[ni], 16); s[ni] += __shfl_xor(s[ni], 32);
        q[ni] += __shfl_xor(q[ni], 16); q[ni] += __shfl_xor(q[ni], 32);
    }
    float* redS = (float*)Asm;
    float* redQ = redS + 256;
    if (lane < 16) {
        #pragma unroll
        for (int ni = 0; ni < 4; ++ni) {
            int c = wn * 64 + ni * 16 + lane;
            redS[wm * 128 + c] = s[ni];
            redQ[wm * 128 + c] = q[ni];
        }
    }
    __syncthreads();
    if (t < 128) {
        float S = redS[t] + redS[128 + t];
        float Q = redQ[t] + redQ[128 + t];
        partial[(size_t)blockIdx.x * 1024 + blockIdx.y * 128 + t]       = S;
        partial[(size_t)blockIdx.x * 1024 + 512 + blockIdx.y * 128 + t] = Q;
    }

    // H write (bf16)
    #pragma unroll
    for (int mi = 0; mi < 4; ++mi) {
        #pragma unroll
        for (int ni = 0; ni < 4; ++ni) {
            int col   = n0 + wn * 64 + ni * 16 + (lane & 15);
            int rbase = m0 + wm * 64 + mi * 16 + (lane >> 4) * 4;
            #pragma unroll
            for (int r = 0; r < 4; ++r)
                H[(size_t)(rbase + r) * COUT + col] = f2bf(acc[mi][ni][r]);
        }
    }
}

// ---------------------------------------------------------------------------
// Kernel C': parallel BN finalize — one block per column (512 blocks x 128
// threads). 128 partial-loads issued in parallel, shfl tree reduce.
// ---------------------------------------------------------------------------
__global__ __launch_bounds__(128) void bn_finalize_kernel(const float* __restrict__ partial,
                                                          const float* __restrict__ gamma,
                                                          const float* __restrict__ beta,
                                                          float* __restrict__ scale,
                                                          float* __restrict__ shift,
                                                          float invN) {
    __shared__ float sS[2], sQ[2];
    int c = blockIdx.x;                    // 0..511
    int p = threadIdx.x;                   // 0..127 (nparts == 128)
    float S = partial[(size_t)p * 1024 + c];
    float Q = partial[(size_t)p * 1024 + 512 + c];
    #pragma unroll
    for (int off = 1; off < 64; off <<= 1) {
        S += __shfl_xor(S, off);
        Q += __shfl_xor(Q, off);
    }
    int lane = p & 63, w = p >> 6;
    if (lane == 0) { sS[w] = S; sQ[w] = Q; }
    __syncthreads();
    if (p == 0) {
        float Sf = sS[0] + sS[1];
        float Qf = sQ[0] + sQ[1];
        float mean = Sf * invN;
        float var  = fmaf(Qf, invN, -mean * mean);
        float inv  = rsqrtf(var + 1e-5f);
        float sc   = gamma[c] * inv;
        scale[c] = sc;
        shift[c] = fmaf(-mean, sc, beta[c]);
    }
}

// ---------------------------------------------------------------------------
// Kernel D': normalize + relu + scatter. 1024 blocks x 32 rows each;
// 8 threads/row, ushort8 H loads, scale/shift staged in LDS.
// ---------------------------------------------------------------------------
__global__ __launch_bounds__(256) void out_kernel(const ushort* __restrict__ H,
                                                  const int* __restrict__ inv4,
                                                  const float* __restrict__ scale,
                                                  const float* __restrict__ shift,
                                                  float* __restrict__ out, int rows) {
    __shared__ float scl[512], sht[512];
    int t = threadIdx.x;
    scl[t]       = scale[t];
    scl[t + 256] = scale[t + 256];
    sht[t]       = shift[t];
    sht[t + 256] = shift[t + 256];
    __syncthreads();

    int r = blockIdx.x * 32 + (t >> 3);    // this thread's row
    if (r >= rows) return;
    int c0 = (t & 7) * 8;                  // 8-col base; strides of 64 below
    int j = inv4[r];
    float* orow = out + (size_t)r * COUT;

    if (j >= 0) {
        const ushort* hrow = H + (size_t)j * COUT;
        #pragma unroll
        for (int i = 0; i < 8; ++i) {
            int c = c0 + i * 64;
            bf16x8 h = *reinterpret_cast<const bf16x8*>(hrow + c);
            float4 a, b;
            a.x = fmaxf(fmaf(bf2f((ushort)h[0]), scl[c + 0], sht[c + 0]), 0.f);
            a.y = fmaxf(fmaf(bf2f((ushort)h[1]), scl[c + 1], sht[c + 1]), 0.f);
            a.z = fmaxf(fmaf(bf2f((ushort)h[2]), scl[c + 2], sht[c + 2]), 0.f);
            a.w = fmaxf(fmaf(bf2f((ushort)h[3]), scl[c + 3], sht[c + 3]), 0.f);
            b.x = fmaxf(fmaf(bf2f((ushort)h[4]), scl[c + 4], sht[c + 4]), 0.f);
            b.y = fmaxf(fmaf(bf2f((ushort)h[5]), scl[c + 5], sht[c + 5]), 0.f);
            b.z = fmaxf(fmaf(bf2f((ushort)h[6]), scl[c + 6], sht[c + 6]), 0.f);
            b.w = fmaxf(fmaf(bf2f((ushort)h[7]), scl[c + 7], sht[c + 7]), 0.f);
            *reinterpret_cast<float4*>(orow + c)     = a;
            *reinterpret_cast<float4*>(orow + c + 4) = b;
        }
    } else {
        #pragma unroll
        for (int i = 0; i < 8; ++i) {
            int c = c0 + i * 64;
            float4 a, b;
            a.x = fmaxf(sht[c + 0], 0.f);
            a.y = fmaxf(sht[c + 1], 0.f);
            a.z = fmaxf(sht[c + 2], 0.f);
            a.w = fmaxf(sht[c + 3], 0.f);
            b.x = fmaxf(sht[c + 4], 0.f);
            b.y = fmaxf(sht[c + 5], 0.f);
            b.z = fmaxf(sht[c + 6], 0.f);
            b.w = fmaxf(sht[c + 7], 0.f);
            *reinterpret_cast<float4*>(orow + c)     = a;
            *reinterpret_cast<float4*>(orow + c + 4) = b;
        }
    }
}

// ---------------------------------------------------------------------------
extern "C" void kernel_launch(void* const* d_in, const int* in_sizes, int n_in,
                              void* d_out, int out_size, void* d_ws, size_t ws_size,
                              hipStream_t stream) {
    const float* data   = (const float*)d_in[0];
    const float* weight = (const float*)d_in[1];
    const float* gamma  = (const float*)d_in[2];
    const float* beta   = (const float*)d_in[3];
    const int*   idx5   = (const int*)d_in[4];
    const int*   idx4   = (const int*)d_in[5];

    const int n_i5 = in_sizes[4];        // 65536
    const int n_i4 = in_sizes[5];        // 16384
    const int G2   = n_i4;
    const int rows = out_size / COUT;    // 32768
    const int M    = G2;                 // 16384
    const int MB   = M / 128;            // 128 m-tiles

    // workspace layout
    char* w = (char*)d_ws;
    ushort* P      = (ushort*)w;                        w += (size_t)G2 * CIN * sizeof(ushort);    // 8 MiB
    ushort* H      = (ushort*)w;                        w += (size_t)G2 * COUT * sizeof(ushort);   // 16 MiB
    ushort* Wb     = (ushort*)w;                        w += (size_t)COUT * CIN * sizeof(ushort);  // 0.25 MiB
    float* partial = (float*)w;                         w += (size_t)MB * 1024 * sizeof(float);    // 512 KiB
    float* scale   = (float*)w;                         w += COUT * sizeof(float);
    float* shift   = (float*)w;                         w += COUT * sizeof(float);
    int*   inv4    = (int*)w;                           w += (size_t)rows * sizeof(int);           // 128 KiB

    // A: pool (G2/4 blocks) + W->bf16 (32 blocks) + inv4 build (64 blocks)
    pool_prep_kernel<<<G2 / 4 + 32 + (n_i4 + 255) / 256, 256, 0, stream>>>(
        data, idx5, n_i5, idx4, n_i4, weight, Wb, P, G2, inv4, rows);

    // B: MFMA GEMM + fused stats
    {
        dim3 grid(MB, COUT / 128);
        mfma_gemm_kernel<<<grid, 256, 0, stream>>>(P, Wb, H, partial);
    }
    // C': parallel BN finalize (one block per column)
    bn_finalize_kernel<<<COUT, 128, 0, stream>>>(partial, gamma, beta, scale, shift,
                                                 1.0f / (float)rows);
    // D': normalize + relu + scatter (32 rows per block)
    out_kernel<<<(rows + 31) / 32, 256, 0, stream>>>(H, inv4, scale, shift,
                                                     (float*)d_out, rows);
}